// Round 8
// baseline (211.300 us; speedup 1.0000x reference)
//
#include <hip/hip_runtime.h>

#define NTOKEN 50257
#define NTOK_PAD 50304   // 786 * 64
#define SB 1024
#define C_LOG2PI 235.2482644909f  // 0.5 * 256 * log(2*pi)

typedef __attribute__((ext_vector_type(8))) short bf16x8;
typedef __attribute__((ext_vector_type(4))) short s16x4;
typedef __attribute__((ext_vector_type(4))) float f32x4;
typedef float f32x4u __attribute__((ext_vector_type(4), aligned(4)));

#define MFMA16(a, b, c) __builtin_amdgcn_mfma_f32_16x16x32_bf16((a), (b), (c), 0, 0, 0)

__device__ __forceinline__ unsigned short f2bf(float f) {
  unsigned int u = __float_as_uint(f);
  u += 0x7fffu + ((u >> 16) & 1u);   // round-to-nearest-even
  return (unsigned short)(u >> 16);
}
__device__ __forceinline__ float bf2f(unsigned short s) {
  return __uint_as_float(((unsigned int)s) << 16);
}

// ---------------- workspace layout (bytes) ----------------
#define HB_OFF   0u            // 1024*256*2 = 524288 (linear)
#define HN_OFF   524288u       // 1024*4
#define DM_OFF   528384u       // 256*4
#define CV_OFF   529408u       // 256*4
#define W1B_OFF  530432u       // 65536*2
#define W2B_OFF  661504u       // 65536*2 (end = 792576)

// ---------------- prep: h, weights, diag + cvec ----------------
// grid = 32 (h) + 64 (conv_w) + 64 (diag/cvec) = 160 blocks x 256
__global__ __launch_bounds__(256) void prep_all(
    const float* __restrict__ h, const float* __restrict__ W1x,
    const float* __restrict__ W2, const float* __restrict__ w1t,
    const float* __restrict__ b2, short* __restrict__ hb,
    float* __restrict__ hnorm, short* __restrict__ W1b,
    short* __restrict__ W2b, float* __restrict__ dM,
    float* __restrict__ cvec) {
  const int bid = blockIdx.x;
  const int tid = threadIdx.x;
  if (bid < 32) {
    // ---- h -> linear bf16 + norms ----
    int row = bid * 32 + (tid >> 3);
    int c0 = (tid & 7) * 32;
    float ss = 0.f;
    #pragma unroll
    for (int g = 0; g < 4; ++g) {
      int c = c0 + g * 8;
      const float4* p = (const float4*)&h[row * 256 + c];
      float4 x = p[0], y = p[1];
      float v[8] = {x.x, x.y, x.z, x.w, y.x, y.y, y.z, y.w};
      bf16x8 o;
      #pragma unroll
      for (int j = 0; j < 8; ++j) { ss += v[j] * v[j]; o[j] = (short)f2bf(v[j]); }
      *(bf16x8*)&hb[row * 256 + c] = o;
    }
    ss += __shfl_xor(ss, 1); ss += __shfl_xor(ss, 2); ss += __shfl_xor(ss, 4);
    if ((tid & 7) == 0) hnorm[row] = ss;
  } else if (bid < 96) {
    // ---- W1x, W2 -> bf16 ----
    int base = ((bid - 32) * 256 + tid) * 4;
    float4 a = *(const float4*)&W1x[base];
    short4 o1;
    o1.x = (short)f2bf(a.x); o1.y = (short)f2bf(a.y);
    o1.z = (short)f2bf(a.z); o1.w = (short)f2bf(a.w);
    *(short4*)&W1b[base] = o1;
    float4 b = *(const float4*)&W2[base];
    short4 o2;
    o2.x = (short)f2bf(b.x); o2.y = (short)f2bf(b.y);
    o2.z = (short)f2bf(b.z); o2.w = (short)f2bf(b.w);
    *(short4*)&W2b[base] = o2;
  } else {
    // ---- dM[j] = sum_i W1x[j,i]*W2[i,j]; cvec[j] = .5*(W1x[j,:]·b2 + w1t[j]) ----
    int j = (bid - 96) * 4 + (tid >> 6);
    int lane = tid & 63;
    float s = 0.f, s2 = 0.f;
    #pragma unroll
    for (int t = 0; t < 4; ++t) {
      int i = lane + t * 64;
      float w1 = W1x[j * 256 + i];
      s += w1 * W2[i * 256 + j];
      s2 += w1 * b2[i];
    }
    #pragma unroll
    for (int d = 1; d < 64; d <<= 1) {
      s += __shfl_xor(s, d);
      s2 += __shfl_xor(s2, d);
    }
    if (lane == 0) { dM[j] = s; cvec[j] = 0.5f * (s2 + w1t[j]); }
  }
}

// ---- 64x256 LDS tile (token rows, XOR-swizzled 16B groups) x W^T ----
// acc[m][n] = MFMA16(Wfrag[m], Tfrag[n]) -> D[wcol][token]:
//   wcol = cb + m*16 + rg + r (contiguous in r), token = n*16 + l15.
__device__ __forceinline__ void mmT(const short* T, const short* __restrict__ W,
                                    int l15, int kof, int cb, f32x4 acc[4][4]) {
  const f32x4 vz = {0.f, 0.f, 0.f, 0.f};
  #pragma unroll
  for (int m = 0; m < 4; ++m)
    #pragma unroll
    for (int n = 0; n < 4; ++n) acc[m][n] = vz;
  #pragma unroll
  for (int s = 0; s < 8; ++s) {
    int k0 = s * 32 + kof;
    int ks = k0 ^ ((l15 & 7) << 3);
    bf16x8 w[4], z[4];
    #pragma unroll
    for (int m = 0; m < 4; ++m)
      w[m] = *(const bf16x8*)&W[(cb + m * 16 + l15) * 256 + k0];
    #pragma unroll
    for (int n = 0; n < 4; ++n)
      z[n] = *(const bf16x8*)&T[(n * 16 + l15) * 256 + ks];
    #pragma unroll
    for (int m = 0; m < 4; ++m)
      #pragma unroll
      for (int n = 0; n < 4; ++n) acc[m][n] = MFMA16(w[m], z[n], acc[m][n]);
  }
}

// ---- emb -> zt staging: slot-linear LDS writes (conflict-free), XOR on the
// global read side. slot o = tid + k*256; row = o>>5, blk = o&31,
// data group g = (blk&24) | ((blk&7)^(row&7)). scratch[row][tid&31] = |v|^2.
__device__ __forceinline__ void stage_z(const float* __restrict__ emb,
                                        short* zt, float (*scratch)[33],
                                        int tokbase, int tid) {
  #pragma unroll
  for (int k = 0; k < 8; ++k) {
    int o = tid + k * 256;
    int row = o >> 5, blk = o & 31;
    int g = (blk & 24) | ((blk & 7) ^ (row & 7));
    int gtok = tokbase + row;
    float v[8];
    if (gtok < NTOKEN) {
      const float4* p = (const float4*)&emb[(size_t)gtok * 256 + g * 8];
      float4 x = p[0], y = p[1];
      v[0] = x.x; v[1] = x.y; v[2] = x.z; v[3] = x.w;
      v[4] = y.x; v[5] = y.y; v[6] = y.z; v[7] = y.w;
    } else {
      #pragma unroll
      for (int j = 0; j < 8; ++j) v[j] = 0.f;
    }
    bf16x8 ob;
    float ss = 0.f;
    #pragma unroll
    for (int j = 0; j < 8; ++j) { ss += v[j] * v[j]; ob[j] = (short)f2bf(v[j]); }
    *(bf16x8*)((char*)zt + o * 16) = ob;
    scratch[row][tid & 31] = ss;
  }
}

// ---------------- mega kernel: one block per 64-token tile ----------------
// CNF for 64 tokens (once) + logp GEMM vs all 1024 h-rows.
// XCD chunking: xcd = bid&7 owns contiguous tc range (98/99 tiles) ->
// adjacent out column-chunks merge write-boundary lines in its L2.
__global__ __launch_bounds__(256) void mega2(
    const float* __restrict__ emb, const short* __restrict__ hb,
    const short* __restrict__ W1b, const short* __restrict__ W2b,
    const float* __restrict__ dM, const float* __restrict__ cvec,
    const float* __restrict__ b1, const float* __restrict__ hnorm,
    float* __restrict__ out) {
  __shared__ short zt[64 * 256];       // 32 KB: z0 -> sp -> G -> z0 again
  __shared__ float scratch[64][33];    // 8.4 KB: per-row |z|^2 partials
  __shared__ float trs[4][64];
  __shared__ float cbl[64];
  const int bid = blockIdx.x;          // 786 = 8*98 + 2
  const int xcd = bid & 7, idx = bid >> 3;
  const int tc = (xcd < 2) ? xcd * 99 + idx : 198 + (xcd - 2) * 98 + idx;
  const int tokbase = tc * 64;

  const int tid = threadIdx.x;
  const int lane = tid & 63, wv = tid >> 6;
  const int l15 = lane & 15, rg = (lane >> 4) * 4, kof = (lane >> 4) * 8;
  const int cb = wv * 64;

  // ---- stage z0 ----
  stage_z(emb, zt, scratch, tokbase, tid);
  f32x4 b1v[4], dmv[4];
  #pragma unroll
  for (int m = 0; m < 4; ++m) {
    b1v[m] = *(const f32x4*)&b1[cb + m * 16 + rg];
    dmv[m] = *(const f32x4*)&dM[cb + m * 16 + rg];
  }
  __syncthreads();

  f32x4 acc[4][4];
  unsigned int p0a[4][4], p0b[4][4];   // pre0 packed 2xbf16 (32 VGPR)

  // ---- pass A: pre0^T = W1 x z0; tr0; sp -> zt ----
  mmT(zt, W1b, l15, kof, cb, acc);
  __syncthreads();   // all waves done reading z0
  {
    float p[4] = {0.f, 0.f, 0.f, 0.f};
    #pragma unroll
    for (int m = 0; m < 4; ++m)
      #pragma unroll
      for (int n = 0; n < 4; ++n) {
        s16x4 spv;
        float pre[4];
        #pragma unroll
        for (int r = 0; r < 4; ++r) {
          pre[r] = acc[m][n][r] + b1v[m][r];
          float e = __expf(-fabsf(pre[r]));
          float rc = __fdividef(1.f, 1.f + e);
          p[n] += ((pre[r] >= 0.f) ? rc : e * rc) * dmv[m][r];
          spv[r] = (short)f2bf(fmaxf(pre[r], 0.f) + __logf(1.f + e));
        }
        p0a[m][n] = (unsigned int)f2bf(pre[0]) | ((unsigned int)f2bf(pre[1]) << 16);
        p0b[m][n] = (unsigned int)f2bf(pre[2]) | ((unsigned int)f2bf(pre[3]) << 16);
        int token = n * 16 + l15;
        int colb = (cb + m * 16 + rg) * 2;
        *(s16x4*)((char*)zt + token * 512 + (colb ^ ((token & 7) << 4))) = spv;
      }
    #pragma unroll
    for (int n = 0; n < 4; ++n) {
      p[n] += __shfl_xor(p[n], 16);
      p[n] += __shfl_xor(p[n], 32);
    }
    if (lane < 16)
      #pragma unroll
      for (int n = 0; n < 4; ++n) trs[wv][n * 16 + l15] = p[n];
  }
  __syncthreads();

  // ---- pass B: G = sp @ W2^T (no bias) -> zt ----
  mmT(zt, W2b, l15, kof, cb, acc);
  __syncthreads();   // all waves done reading sp
  #pragma unroll
  for (int m = 0; m < 4; ++m)
    #pragma unroll
    for (int n = 0; n < 4; ++n) {
      s16x4 gv;
      #pragma unroll
      for (int r = 0; r < 4; ++r) gv[r] = (short)f2bf(acc[m][n][r]);
      int token = n * 16 + l15;
      int colb = (cb + m * 16 + rg) * 2;
      *(s16x4*)((char*)zt + token * 512 + (colb ^ ((token & 7) << 4))) = gv;
    }
  __syncthreads();

  // ---- pass C: H = G @ W1^T; pre1 = pre0 + 0.5*H + cvec; tr1 ----
  mmT(zt, W1b, l15, kof, cb, acc);
  __syncthreads();   // all waves done reading G; zt free for re-stage
  {
    f32x4 cvv[4];
    #pragma unroll
    for (int m = 0; m < 4; ++m) cvv[m] = *(const f32x4*)&cvec[cb + m * 16 + rg];
    float p[4] = {0.f, 0.f, 0.f, 0.f};
    #pragma unroll
    for (int m = 0; m < 4; ++m)
      #pragma unroll
      for (int n = 0; n < 4; ++n) {
        float pr0[4] = {bf2f((unsigned short)(p0a[m][n] & 0xffffu)),
                        bf2f((unsigned short)(p0a[m][n] >> 16)),
                        bf2f((unsigned short)(p0b[m][n] & 0xffffu)),
                        bf2f((unsigned short)(p0b[m][n] >> 16))};
        #pragma unroll
        for (int r = 0; r < 4; ++r) {
          float pre = pr0[r] + 0.5f * acc[m][n][r] + cvv[m][r];
          float e = __expf(-fabsf(pre));
          float rc = __fdividef(1.f, 1.f + e);
          p[n] += ((pre >= 0.f) ? rc : e * rc) * dmv[m][r];
        }
      }
    #pragma unroll
    for (int n = 0; n < 4; ++n) {
      p[n] += __shfl_xor(p[n], 16);
      p[n] += __shfl_xor(p[n], 32);
    }
    if (lane < 16)
      #pragma unroll
      for (int n = 0; n < 4; ++n) trs[wv][n * 16 + l15] += p[n];
  }
  // ---- re-stage z0 (emb is L2-hot) + norms ----
  stage_z(emb, zt, scratch, tokbase, tid);
  __syncthreads();

  if (tid < 64) {
    float ss = 0.f;
    #pragma unroll 8
    for (int i = 0; i < 32; ++i) ss += scratch[tid][i];
    float t = trs[0][tid] + trs[1][tid] + trs[2][tid] + trs[3][tid];
    cbl[tid] = -0.5f * ss - C_LOG2PI + 0.5f * t;
  }
  __syncthreads();

  // ---- logp GEMM: swapped operands -> lane holds 4 contiguous tokens ----
  // acc2[n][m] = MFMA(z[n], a[m]): D row = token (rg+r), col = h-row (l15)
  #pragma unroll 1
  for (int it = 0; it < 4; ++it) {
    const int rowbase = it * 256 + wv * 64;
    f32x4 acc2[4][4];
    const f32x4 vz = {0.f, 0.f, 0.f, 0.f};
    #pragma unroll
    for (int n = 0; n < 4; ++n)
      #pragma unroll
      for (int m = 0; m < 4; ++m) acc2[n][m] = vz;
    #pragma unroll
    for (int s = 0; s < 8; ++s) {
      int k0 = s * 32 + kof;
      int ks = k0 ^ ((l15 & 7) << 3);
      bf16x8 z[4], a[4];
      #pragma unroll
      for (int n = 0; n < 4; ++n)
        z[n] = *(const bf16x8*)&zt[(n * 16 + l15) * 256 + ks];
      #pragma unroll
      for (int m = 0; m < 4; ++m)
        a[m] = *(const bf16x8*)&hb[(rowbase + m * 16 + l15) * 256 + k0];
      #pragma unroll
      for (int n = 0; n < 4; ++n)
        #pragma unroll
        for (int m = 0; m < 4; ++m) acc2[n][m] = MFMA16(z[n], a[m], acc2[n][m]);
    }
    #pragma unroll
    for (int m = 0; m < 4; ++m) {
      int gr = rowbase + m * 16 + l15;
      float hn = 0.5f * hnorm[gr];
      #pragma unroll
      for (int n = 0; n < 4; ++n) {
        int gt = tokbase + n * 16 + rg;
        f32x4 cb4 = *(const f32x4*)&cbl[n * 16 + rg];
        f32x4 v = acc2[n][m];
        #pragma unroll
        for (int r = 0; r < 4; ++r) v[r] += cb4[r] - hn;
        float* op = out + (size_t)gr * NTOKEN + gt;
        if (gt + 4 <= NTOKEN) {
          *(f32x4u*)op = v;
        } else {
          #pragma unroll
          for (int r = 0; r < 4; ++r)
            if (gt + r < NTOKEN) op[r] = v[r];
        }
      }
    }
  }
}

// ---------------- launcher ----------------
extern "C" void kernel_launch(void* const* d_in, const int* in_sizes, int n_in,
                              void* d_out, int out_size, void* d_ws, size_t ws_size,
                              hipStream_t stream) {
  const float* h   = (const float*)d_in[0];
  const float* emb = (const float*)d_in[1];
  const float* W1x = (const float*)d_in[2];
  const float* w1t = (const float*)d_in[3];
  const float* b1  = (const float*)d_in[4];
  const float* W2  = (const float*)d_in[5];
  const float* b2  = (const float*)d_in[6];
  float* out = (float*)d_out;

  char* ws = (char*)d_ws;
  short* hb    = (short*)(ws + HB_OFF);
  float* hnorm = (float*)(ws + HN_OFF);
  float* dM    = (float*)(ws + DM_OFF);
  float* cvec  = (float*)(ws + CV_OFF);
  short* W1b   = (short*)(ws + W1B_OFF);
  short* W2b   = (short*)(ws + W2B_OFF);

  prep_all<<<160, 256, 0, stream>>>(h, W1x, W2, w1t, b2, hb, hnorm, W1b, W2b,
                                    dM, cvec);
  mega2<<<786, 256, 0, stream>>>(emb, hb, W1b, W2b, dM, cvec, b1, hnorm, out);
}

// Round 9
// 207.577 us; speedup vs baseline: 1.0179x; 1.0179x over previous
//
#include <hip/hip_runtime.h>

#define NTOKEN 50257
#define NTOK_PAD 50304   // 786 * 64
#define SB 1024
#define C_LOG2PI 235.2482644909f  // 0.5 * 256 * log(2*pi)

typedef __attribute__((ext_vector_type(8))) short bf16x8;
typedef __attribute__((ext_vector_type(4))) short s16x4;
typedef __attribute__((ext_vector_type(4))) float f32x4;
typedef float f32x4u __attribute__((ext_vector_type(4), aligned(4)));

#define MFMA16(a, b, c) __builtin_amdgcn_mfma_f32_16x16x32_bf16((a), (b), (c), 0, 0, 0)

__device__ __forceinline__ unsigned short f2bf(float f) {
  unsigned int u = __float_as_uint(f);
  u += 0x7fffu + ((u >> 16) & 1u);   // round-to-nearest-even
  return (unsigned short)(u >> 16);
}
__device__ __forceinline__ float bf2f(unsigned short s) {
  return __uint_as_float(((unsigned int)s) << 16);
}
__device__ __forceinline__ void gload16(const void* g, void* l) {
  __builtin_amdgcn_global_load_lds(
      (const __attribute__((address_space(1))) unsigned int*)g,
      (__attribute__((address_space(3))) unsigned int*)l, 16, 0, 0);
}

// ---------------- workspace layout (bytes) ----------------
#define HB_OFF   0u            // 1024*256*2  = 524288 (linear)
#define ZB_OFF   524288u       // 50304*256*2 = 25755648 (pre-swizzled rows)
#define HN_OFF   26279936u     // 1024*4
#define CB_OFF   26284032u     // 50304*4
#define DM_OFF   26485248u     // 256*4
#define CV_OFF   26486272u     // 256*4
#define W1B_OFF  26487296u     // 65536*2
#define W2B_OFF  26618368u     // 65536*2 (end = 26749440)

// ---------------- prep: h, weights, diag + cvec ----------------
__global__ __launch_bounds__(256) void prep_all(
    const float* __restrict__ h, const float* __restrict__ W1x,
    const float* __restrict__ W2, const float* __restrict__ w1t,
    const float* __restrict__ b2, short* __restrict__ hb,
    float* __restrict__ hnorm, short* __restrict__ W1b,
    short* __restrict__ W2b, float* __restrict__ dM,
    float* __restrict__ cvec) {
  const int bid = blockIdx.x;
  const int tid = threadIdx.x;
  if (bid < 32) {
    // ---- h -> linear bf16 + norms ----
    int row = bid * 32 + (tid >> 3);
    int c0 = (tid & 7) * 32;
    float ss = 0.f;
    #pragma unroll
    for (int g = 0; g < 4; ++g) {
      int c = c0 + g * 8;
      const float4* p = (const float4*)&h[row * 256 + c];
      float4 x = p[0], y = p[1];
      float v[8] = {x.x, x.y, x.z, x.w, y.x, y.y, y.z, y.w};
      bf16x8 o;
      #pragma unroll
      for (int j = 0; j < 8; ++j) { ss += v[j] * v[j]; o[j] = (short)f2bf(v[j]); }
      *(bf16x8*)&hb[row * 256 + c] = o;
    }
    ss += __shfl_xor(ss, 1); ss += __shfl_xor(ss, 2); ss += __shfl_xor(ss, 4);
    if ((tid & 7) == 0) hnorm[row] = ss;
  } else if (bid < 96) {
    // ---- W1x, W2 -> bf16 ----
    int base = ((bid - 32) * 256 + tid) * 4;
    float4 a = *(const float4*)&W1x[base];
    short4 o1;
    o1.x = (short)f2bf(a.x); o1.y = (short)f2bf(a.y);
    o1.z = (short)f2bf(a.z); o1.w = (short)f2bf(a.w);
    *(short4*)&W1b[base] = o1;
    float4 b = *(const float4*)&W2[base];
    short4 o2;
    o2.x = (short)f2bf(b.x); o2.y = (short)f2bf(b.y);
    o2.z = (short)f2bf(b.z); o2.w = (short)f2bf(b.w);
    *(short4*)&W2b[base] = o2;
  } else {
    // ---- dM[j] = sum_i W1x[j,i]*W2[i,j]; cvec[j] = .5*(W1x[j,:]·b2 + w1t[j]) ----
    int j = (bid - 96) * 4 + (tid >> 6);
    int lane = tid & 63;
    float s = 0.f, s2 = 0.f;
    #pragma unroll
    for (int t = 0; t < 4; ++t) {
      int i = lane + t * 64;
      float w1 = W1x[j * 256 + i];
      s += w1 * W2[i * 256 + j];
      s2 += w1 * b2[i];
    }
    #pragma unroll
    for (int d = 1; d < 64; d <<= 1) {
      s += __shfl_xor(s, d);
      s2 += __shfl_xor(s2, d);
    }
    if (lane == 0) { dM[j] = s; cvec[j] = 0.5f * (s2 + w1t[j]); }
  }
}

// ---- 64x256 LDS tile (token rows, XOR-swizzled 16B groups) x W^T ----
// acc[m][n] = MFMA16(Wfrag[m], Tfrag[n]) -> D[wcol][token]:
//   wcol = cb + m*16 + rg + r (contiguous in r), token = n*16 + l15.
__device__ __forceinline__ void mmT(const short* T, const short* __restrict__ W,
                                    int l15, int kof, int cb, f32x4 acc[4][4]) {
  const f32x4 vz = {0.f, 0.f, 0.f, 0.f};
  #pragma unroll
  for (int m = 0; m < 4; ++m)
    #pragma unroll
    for (int n = 0; n < 4; ++n) acc[m][n] = vz;
  #pragma unroll
  for (int s = 0; s < 8; ++s) {
    int k0 = s * 32 + kof;
    int ks = k0 ^ ((l15 & 7) << 3);
    bf16x8 w[4], z[4];
    #pragma unroll
    for (int m = 0; m < 4; ++m)
      w[m] = *(const bf16x8*)&W[(cb + m * 16 + l15) * 256 + k0];
    #pragma unroll
    for (int n = 0; n < 4; ++n)
      z[n] = *(const bf16x8*)&T[(n * 16 + l15) * 256 + ks];
    #pragma unroll
    for (int m = 0; m < 4; ++m)
      #pragma unroll
      for (int n = 0; n < 4; ++n) acc[m][n] = MFMA16(w[m], z[n], acc[m][n]);
  }
}

// ---------------- CNF: one 32 KB tile, z0 -> sp -> G in place ----------------
// Also produces zb (pre-swizzled bf16 copy of z0) and cbias.
__global__ __launch_bounds__(256) void cnf3(
    const float* __restrict__ emb, const short* __restrict__ W1b,
    const short* __restrict__ W2b, const float* __restrict__ dM,
    const float* __restrict__ cvec, const float* __restrict__ b1,
    short* __restrict__ zb, float* __restrict__ cbias) {
  __shared__ short zt[64 * 256];    // 32 KB: z0 -> sp -> G
  __shared__ float trs[4][64];
  __shared__ float znl[64];
  const int tid = threadIdx.x;
  const int lane = tid & 63, wv = tid >> 6;
  const int l15 = lane & 15, rg = (lane >> 4) * 4, kof = (lane >> 4) * 8;
  const int cb = wv * 64;
  const int tokbase = blockIdx.x * 64;

  // ---- stage z0: slot-linear LDS writes (conflict-free), XOR folded into
  // the global read; also emit zb (coalesced) + row norms via 32-lane shfl ----
  #pragma unroll
  for (int k = 0; k < 8; ++k) {
    int o = tid + k * 256;
    int row = o >> 5, blk = o & 31;
    int g = (blk & 24) | ((blk & 7) ^ (row & 7));
    int gtok = tokbase + row;
    float v[8];
    if (gtok < NTOKEN) {
      const float4* p = (const float4*)&emb[(size_t)gtok * 256 + g * 8];
      float4 x = p[0], y = p[1];
      v[0] = x.x; v[1] = x.y; v[2] = x.z; v[3] = x.w;
      v[4] = y.x; v[5] = y.y; v[6] = y.z; v[7] = y.w;
    } else {
      #pragma unroll
      for (int j = 0; j < 8; ++j) v[j] = 0.f;
    }
    bf16x8 ob;
    float ss = 0.f;
    #pragma unroll
    for (int j = 0; j < 8; ++j) { ss += v[j] * v[j]; ob[j] = (short)f2bf(v[j]); }
    *(bf16x8*)((char*)zt + o * 16) = ob;
    *(bf16x8*)&zb[(size_t)tokbase * 256 + o * 8] = ob;
    ss += __shfl_xor(ss, 1); ss += __shfl_xor(ss, 2); ss += __shfl_xor(ss, 4);
    ss += __shfl_xor(ss, 8); ss += __shfl_xor(ss, 16);
    if ((tid & 31) == 0) znl[(tid >> 5) + k * 8] = ss;
  }
  f32x4 b1v[4], dmv[4];
  #pragma unroll
  for (int m = 0; m < 4; ++m) {
    b1v[m] = *(const f32x4*)&b1[cb + m * 16 + rg];
    dmv[m] = *(const f32x4*)&dM[cb + m * 16 + rg];
  }
  __syncthreads();

  f32x4 acc[4][4];
  unsigned int p0a[4][4], p0b[4][4];   // pre0 packed 2xbf16 (32 VGPR)

  // ---- pass A: pre0^T = W1 x z0; tr0; sp -> zt ----
  mmT(zt, W1b, l15, kof, cb, acc);
  __syncthreads();   // all waves done reading z0
  {
    float p[4] = {0.f, 0.f, 0.f, 0.f};
    #pragma unroll
    for (int m = 0; m < 4; ++m)
      #pragma unroll
      for (int n = 0; n < 4; ++n) {
        s16x4 spv;
        float pre[4];
        #pragma unroll
        for (int r = 0; r < 4; ++r) {
          pre[r] = acc[m][n][r] + b1v[m][r];
          float e = __expf(-fabsf(pre[r]));
          float rc = __fdividef(1.f, 1.f + e);
          p[n] += ((pre[r] >= 0.f) ? rc : e * rc) * dmv[m][r];
          spv[r] = (short)f2bf(fmaxf(pre[r], 0.f) + __logf(1.f + e));
        }
        p0a[m][n] = (unsigned int)f2bf(pre[0]) | ((unsigned int)f2bf(pre[1]) << 16);
        p0b[m][n] = (unsigned int)f2bf(pre[2]) | ((unsigned int)f2bf(pre[3]) << 16);
        int token = n * 16 + l15;
        int colb = (cb + m * 16 + rg) * 2;
        *(s16x4*)((char*)zt + token * 512 + (colb ^ ((token & 7) << 4))) = spv;
      }
    #pragma unroll
    for (int n = 0; n < 4; ++n) {
      p[n] += __shfl_xor(p[n], 16);
      p[n] += __shfl_xor(p[n], 32);
    }
    if (lane < 16)
      #pragma unroll
      for (int n = 0; n < 4; ++n) trs[wv][n * 16 + l15] = p[n];
  }
  __syncthreads();

  // ---- pass B: G = sp @ W2^T -> zt ----
  mmT(zt, W2b, l15, kof, cb, acc);
  __syncthreads();   // all waves done reading sp
  #pragma unroll
  for (int m = 0; m < 4; ++m)
    #pragma unroll
    for (int n = 0; n < 4; ++n) {
      s16x4 gv;
      #pragma unroll
      for (int r = 0; r < 4; ++r) gv[r] = (short)f2bf(acc[m][n][r]);
      int token = n * 16 + l15;
      int colb = (cb + m * 16 + rg) * 2;
      *(s16x4*)((char*)zt + token * 512 + (colb ^ ((token & 7) << 4))) = gv;
    }
  __syncthreads();

  // ---- pass C: H = G @ W1^T; pre1 = pre0 + 0.5*H + cvec; tr1 ----
  mmT(zt, W1b, l15, kof, cb, acc);
  {
    f32x4 cvv[4];
    #pragma unroll
    for (int m = 0; m < 4; ++m) cvv[m] = *(const f32x4*)&cvec[cb + m * 16 + rg];
    float p[4] = {0.f, 0.f, 0.f, 0.f};
    #pragma unroll
    for (int m = 0; m < 4; ++m)
      #pragma unroll
      for (int n = 0; n < 4; ++n) {
        float pr0[4] = {bf2f((unsigned short)(p0a[m][n] & 0xffffu)),
                        bf2f((unsigned short)(p0a[m][n] >> 16)),
                        bf2f((unsigned short)(p0b[m][n] & 0xffffu)),
                        bf2f((unsigned short)(p0b[m][n] >> 16))};
        #pragma unroll
        for (int r = 0; r < 4; ++r) {
          float pre = pr0[r] + 0.5f * acc[m][n][r] + cvv[m][r];
          float e = __expf(-fabsf(pre));
          float rc = __fdividef(1.f, 1.f + e);
          p[n] += ((pre >= 0.f) ? rc : e * rc) * dmv[m][r];
        }
      }
    #pragma unroll
    for (int n = 0; n < 4; ++n) {
      p[n] += __shfl_xor(p[n], 16);
      p[n] += __shfl_xor(p[n], 32);
    }
    if (lane < 16)
      #pragma unroll
      for (int n = 0; n < 4; ++n) trs[wv][n * 16 + l15] += p[n];
  }
  __syncthreads();

  if (tid < 64) {
    float t = trs[0][tid] + trs[1][tid] + trs[2][tid] + trs[3][tid];
    cbias[tokbase + tid] = -0.5f * znl[tid] - C_LOG2PI + 0.5f * t;
  }
}

// ---------------- big log-prob GEMM ----------------
// Block: 256 h-rows x 64 tokens (4 waves x 64 rows). Swapped MFMA: lane holds
// 4 CONTIGUOUS tokens -> direct f32x4 stores (no patch; WRITE_SIZE-verified
// 202 MB in round 8). One barrier total. XCD scheme: x = bid&7;
// stripe = x>>1, tc = (x&1)*393 + bid>>3 (contiguous tc per XCD).
__global__ __launch_bounds__(256) void logp_kernel(
    const short* __restrict__ hb, const short* __restrict__ zb,
    const float* __restrict__ hnorm, const float* __restrict__ cbias,
    float* __restrict__ out) {
  __shared__ short Bz[64 * 256];   // 32 KB
  const int bid = blockIdx.x;      // 3144 = 393 * 8
  const int x = bid & 7;
  const int stripe = x >> 1;
  const int tc = (x & 1) * 393 + (bid >> 3);
  const int tokbase = tc * 64;
  const int tid = threadIdx.x;
  const int lane = tid & 63, wv = tid >> 6;
  const int l15 = lane & 15, rg = (lane >> 4) * 4, kof = (lane >> 4) * 8;

  // stage B tile (64 tokens, pre-swizzled rows): linear, conflict-free
  {
    const char* bsrc = (const char*)(zb + (size_t)tokbase * 256);
    #pragma unroll
    for (int it = 0; it < 8; ++it) {
      int uoff = wv * 8192 + it * 1024;
      gload16(bsrc + uoff + lane * 16, (char*)Bz + uoff);
    }
  }
  __syncthreads();

  const int rowbase = stripe * 256 + wv * 64;
  f32x4 acc2[4][4];
  const f32x4 vz = {0.f, 0.f, 0.f, 0.f};
  #pragma unroll
  for (int n = 0; n < 4; ++n)
    #pragma unroll
    for (int m = 0; m < 4; ++m) acc2[n][m] = vz;

  #pragma unroll
  for (int s = 0; s < 8; ++s) {
    int k0 = s * 32 + kof;
    int ks = k0 ^ ((l15 & 7) << 3);
    bf16x8 z[4];
    #pragma unroll
    for (int n = 0; n < 4; ++n)
      z[n] = *(const bf16x8*)&Bz[(n * 16 + l15) * 256 + ks];
    #pragma unroll
    for (int m = 0; m < 4; ++m) {
      bf16x8 a = *(const bf16x8*)&hb[(rowbase + m * 16 + l15) * 256 + k0];
      #pragma unroll
      for (int n = 0; n < 4; ++n) acc2[n][m] = MFMA16(z[n], a, acc2[n][m]);
    }
  }

  // direct stores: gr = h-row (l15), gt = 4 contiguous tokens (rg)
  #pragma unroll
  for (int m = 0; m < 4; ++m) {
    int gr = rowbase + m * 16 + l15;
    float hn = 0.5f * hnorm[gr];
    #pragma unroll
    for (int n = 0; n < 4; ++n) {
      int gt = tokbase + n * 16 + rg;
      f32x4 cb4 = *(const f32x4*)&cbias[gt];
      f32x4 v = acc2[n][m];
      #pragma unroll
      for (int r = 0; r < 4; ++r) v[r] += cb4[r] - hn;
      float* op = out + (size_t)gr * NTOKEN + gt;
      if (gt + 4 <= NTOKEN) {
        *(f32x4u*)op = v;
      } else {
        #pragma unroll
        for (int r = 0; r < 4; ++r)
          if (gt + r < NTOKEN) op[r] = v[r];
      }
    }
  }
}

// ---------------- launcher ----------------
extern "C" void kernel_launch(void* const* d_in, const int* in_sizes, int n_in,
                              void* d_out, int out_size, void* d_ws, size_t ws_size,
                              hipStream_t stream) {
  const float* h   = (const float*)d_in[0];
  const float* emb = (const float*)d_in[1];
  const float* W1x = (const float*)d_in[2];
  const float* w1t = (const float*)d_in[3];
  const float* b1  = (const float*)d_in[4];
  const float* W2  = (const float*)d_in[5];
  const float* b2  = (const float*)d_in[6];
  float* out = (float*)d_out;

  char* ws = (char*)d_ws;
  short* hb    = (short*)(ws + HB_OFF);
  short* zb    = (short*)(ws + ZB_OFF);
  float* hnorm = (float*)(ws + HN_OFF);
  float* cbias = (float*)(ws + CB_OFF);
  float* dM    = (float*)(ws + DM_OFF);
  float* cvec  = (float*)(ws + CV_OFF);
  short* W1b   = (short*)(ws + W1B_OFF);
  short* W2b   = (short*)(ws + W2B_OFF);

  prep_all<<<160, 256, 0, stream>>>(h, W1x, W2, w1t, b2, hb, hnorm, W1b, W2b,
                                    dM, cvec);
  cnf3<<<NTOK_PAD / 64, 256, 0, stream>>>(emb, W1b, W2b, dM, cvec, b1, zb,
                                          cbias);
  logp_kernel<<<393 * 8, 256, 0, stream>>>(hb, zb, hnorm, cbias, out);
}

// Round 10
// 198.501 us; speedup vs baseline: 1.0645x; 1.0457x over previous
//
#include <hip/hip_runtime.h>

#define NTOKEN 50257
#define NTOK_PAD 50304   // 1572 * 32
#define SB 1024
#define C_LOG2PI 235.2482644909f  // 0.5 * 256 * log(2*pi)

typedef __attribute__((ext_vector_type(8))) short bf16x8;
typedef __attribute__((ext_vector_type(4))) short s16x4;
typedef __attribute__((ext_vector_type(4))) float f32x4;
typedef float f32x4u __attribute__((ext_vector_type(4), aligned(4)));

#define MFMA16(a, b, c) __builtin_amdgcn_mfma_f32_16x16x32_bf16((a), (b), (c), 0, 0, 0)

__device__ __forceinline__ unsigned short f2bf(float f) {
  unsigned int u = __float_as_uint(f);
  u += 0x7fffu + ((u >> 16) & 1u);   // round-to-nearest-even
  return (unsigned short)(u >> 16);
}
__device__ __forceinline__ float bf2f(unsigned short s) {
  return __uint_as_float(((unsigned int)s) << 16);
}
__device__ __forceinline__ void gload16(const void* g, void* l) {
  __builtin_amdgcn_global_load_lds(
      (const __attribute__((address_space(1))) unsigned int*)g,
      (__attribute__((address_space(3))) unsigned int*)l, 16, 0, 0);
}

// ---------------- workspace layout (bytes) ----------------
#define HB_OFF   0u            // 1024*256*2  = 524288 (linear)
#define ZB_OFF   524288u       // 50304*256*2 = 25755648 (pre-swizzled rows)
#define HN_OFF   26279936u     // 1024*4
#define CB_OFF   26284032u     // 50304*4
#define DM_OFF   26485248u     // 256*4
#define CV_OFF   26486272u     // 256*4
#define W1B_OFF  26487296u     // 65536*2
#define W2B_OFF  26618368u     // 65536*2 (end = 26749440)

// ---------------- prep: h, weights, diag + cvec ----------------
__global__ __launch_bounds__(256) void prep_all(
    const float* __restrict__ h, const float* __restrict__ W1x,
    const float* __restrict__ W2, const float* __restrict__ w1t,
    const float* __restrict__ b2, short* __restrict__ hb,
    float* __restrict__ hnorm, short* __restrict__ W1b,
    short* __restrict__ W2b, float* __restrict__ dM,
    float* __restrict__ cvec) {
  const int bid = blockIdx.x;
  const int tid = threadIdx.x;
  if (bid < 32) {
    // ---- h -> linear bf16 + norms ----
    int row = bid * 32 + (tid >> 3);
    int c0 = (tid & 7) * 32;
    float ss = 0.f;
    #pragma unroll
    for (int g = 0; g < 4; ++g) {
      int c = c0 + g * 8;
      const float4* p = (const float4*)&h[row * 256 + c];
      float4 x = p[0], y = p[1];
      float v[8] = {x.x, x.y, x.z, x.w, y.x, y.y, y.z, y.w};
      bf16x8 o;
      #pragma unroll
      for (int j = 0; j < 8; ++j) { ss += v[j] * v[j]; o[j] = (short)f2bf(v[j]); }
      *(bf16x8*)&hb[row * 256 + c] = o;
    }
    ss += __shfl_xor(ss, 1); ss += __shfl_xor(ss, 2); ss += __shfl_xor(ss, 4);
    if ((tid & 7) == 0) hnorm[row] = ss;
  } else if (bid < 96) {
    // ---- W1x, W2 -> bf16 ----
    int base = ((bid - 32) * 256 + tid) * 4;
    float4 a = *(const float4*)&W1x[base];
    short4 o1;
    o1.x = (short)f2bf(a.x); o1.y = (short)f2bf(a.y);
    o1.z = (short)f2bf(a.z); o1.w = (short)f2bf(a.w);
    *(short4*)&W1b[base] = o1;
    float4 b = *(const float4*)&W2[base];
    short4 o2;
    o2.x = (short)f2bf(b.x); o2.y = (short)f2bf(b.y);
    o2.z = (short)f2bf(b.z); o2.w = (short)f2bf(b.w);
    *(short4*)&W2b[base] = o2;
  } else {
    // ---- dM[j] = sum_i W1x[j,i]*W2[i,j]; cvec[j] = .5*(W1x[j,:]·b2 + w1t[j]) ----
    int j = (bid - 96) * 4 + (tid >> 6);
    int lane = tid & 63;
    float s = 0.f, s2 = 0.f;
    #pragma unroll
    for (int t = 0; t < 4; ++t) {
      int i = lane + t * 64;
      float w1 = W1x[j * 256 + i];
      s += w1 * W2[i * 256 + j];
      s2 += w1 * b2[i];
    }
    #pragma unroll
    for (int d = 1; d < 64; d <<= 1) {
      s += __shfl_xor(s, d);
      s2 += __shfl_xor(s2, d);
    }
    if (lane == 0) { dM[j] = s; cvec[j] = 0.5f * (s2 + w1t[j]); }
  }
}

// ---- 32x256 LDS tile (token rows, XOR-swizzled 16B groups) x W^T ----
// acc[m][n] = MFMA16(Wfrag[m], Tfrag[n]) -> D[wcol][token]:
//   wcol = cb + m*16 + rg + r (contiguous in r), token = n*16 + l15.
__device__ __forceinline__ void mmT32(const short* T, const short* __restrict__ W,
                                      int l15, int kof, int cb, f32x4 acc[4][2]) {
  const f32x4 vz = {0.f, 0.f, 0.f, 0.f};
  #pragma unroll
  for (int m = 0; m < 4; ++m)
    #pragma unroll
    for (int n = 0; n < 2; ++n) acc[m][n] = vz;
  #pragma unroll
  for (int s = 0; s < 8; ++s) {
    int k0 = s * 32 + kof;
    int ks = k0 ^ ((l15 & 7) << 3);
    bf16x8 z[2];
    #pragma unroll
    for (int n = 0; n < 2; ++n)
      z[n] = *(const bf16x8*)&T[(n * 16 + l15) * 256 + ks];
    #pragma unroll
    for (int m = 0; m < 4; ++m) {
      bf16x8 w = *(const bf16x8*)&W[(cb + m * 16 + l15) * 256 + k0];
      #pragma unroll
      for (int n = 0; n < 2; ++n) acc[m][n] = MFMA16(w, z[n], acc[m][n]);
    }
  }
}

// ---------------- CNF: 32-token tile, z0 -> sp -> G in place ----------------
// __launch_bounds__(256,4): force VGPR<=128 -> 16 waves/CU (4 blocks/CU).
// Also produces zb (pre-swizzled bf16 copy of z0) and cbias.
__global__ __launch_bounds__(256, 4) void cnf4(
    const float* __restrict__ emb, const short* __restrict__ W1b,
    const short* __restrict__ W2b, const float* __restrict__ dM,
    const float* __restrict__ cvec, const float* __restrict__ b1,
    short* __restrict__ zb, float* __restrict__ cbias) {
  __shared__ short zt[32 * 256];    // 16 KB: z0 -> sp -> G
  __shared__ float trs[4][32];
  __shared__ float znl[32];
  const int tid = threadIdx.x;
  const int lane = tid & 63, wv = tid >> 6;
  const int l15 = lane & 15, rg = (lane >> 4) * 4, kof = (lane >> 4) * 8;
  const int cb = wv * 64;
  const int tokbase = blockIdx.x * 32;

  // ---- stage z0: slot-linear LDS writes (conflict-free), XOR folded into
  // the global read; also emit zb (coalesced) + row norms via 32-lane shfl ----
  #pragma unroll
  for (int k = 0; k < 4; ++k) {
    int o = tid + k * 256;
    int row = o >> 5, blk = o & 31;
    int g = (blk & 24) | ((blk & 7) ^ (row & 7));
    int gtok = tokbase + row;
    float v[8];
    if (gtok < NTOKEN) {
      const float4* p = (const float4*)&emb[(size_t)gtok * 256 + g * 8];
      float4 x = p[0], y = p[1];
      v[0] = x.x; v[1] = x.y; v[2] = x.z; v[3] = x.w;
      v[4] = y.x; v[5] = y.y; v[6] = y.z; v[7] = y.w;
    } else {
      #pragma unroll
      for (int j = 0; j < 8; ++j) v[j] = 0.f;
    }
    bf16x8 ob;
    float ss = 0.f;
    #pragma unroll
    for (int j = 0; j < 8; ++j) { ss += v[j] * v[j]; ob[j] = (short)f2bf(v[j]); }
    *(bf16x8*)((char*)zt + o * 16) = ob;
    *(bf16x8*)&zb[(size_t)tokbase * 256 + o * 8] = ob;
    ss += __shfl_xor(ss, 1); ss += __shfl_xor(ss, 2); ss += __shfl_xor(ss, 4);
    ss += __shfl_xor(ss, 8); ss += __shfl_xor(ss, 16);
    if ((tid & 31) == 0) znl[(tid >> 5) + k * 8] = ss;
  }
  __syncthreads();

  f32x4 acc[4][2];
  unsigned int p0a[4][2], p0b[4][2];   // pre0 packed 2xbf16 (16 VGPR)

  // ---- pass A: pre0^T = W1 x z0; tr0; sp -> zt ----
  mmT32(zt, W1b, l15, kof, cb, acc);
  __syncthreads();   // all waves done reading z0
  {
    float p[2] = {0.f, 0.f};
    #pragma unroll
    for (int m = 0; m < 4; ++m) {
      f32x4 b1v = *(const f32x4*)&b1[cb + m * 16 + rg];
      f32x4 dmv = *(const f32x4*)&dM[cb + m * 16 + rg];
      #pragma unroll
      for (int n = 0; n < 2; ++n) {
        s16x4 spv;
        float pre[4];
        #pragma unroll
        for (int r = 0; r < 4; ++r) {
          pre[r] = acc[m][n][r] + b1v[r];
          float e = __expf(-fabsf(pre[r]));
          float rc = __fdividef(1.f, 1.f + e);
          p[n] += ((pre[r] >= 0.f) ? rc : e * rc) * dmv[r];
          spv[r] = (short)f2bf(fmaxf(pre[r], 0.f) + __logf(1.f + e));
        }
        p0a[m][n] = (unsigned int)f2bf(pre[0]) | ((unsigned int)f2bf(pre[1]) << 16);
        p0b[m][n] = (unsigned int)f2bf(pre[2]) | ((unsigned int)f2bf(pre[3]) << 16);
        int token = n * 16 + l15;
        int colb = (cb + m * 16 + rg) * 2;
        *(s16x4*)((char*)zt + token * 512 + (colb ^ ((token & 7) << 4))) = spv;
      }
    }
    #pragma unroll
    for (int n = 0; n < 2; ++n) {
      p[n] += __shfl_xor(p[n], 16);
      p[n] += __shfl_xor(p[n], 32);
    }
    if (lane < 16)
      #pragma unroll
      for (int n = 0; n < 2; ++n) trs[wv][n * 16 + l15] = p[n];
  }
  __syncthreads();

  // ---- pass B: G = sp @ W2^T -> zt ----
  mmT32(zt, W2b, l15, kof, cb, acc);
  __syncthreads();   // all waves done reading sp
  #pragma unroll
  for (int m = 0; m < 4; ++m)
    #pragma unroll
    for (int n = 0; n < 2; ++n) {
      s16x4 gv;
      #pragma unroll
      for (int r = 0; r < 4; ++r) gv[r] = (short)f2bf(acc[m][n][r]);
      int token = n * 16 + l15;
      int colb = (cb + m * 16 + rg) * 2;
      *(s16x4*)((char*)zt + token * 512 + (colb ^ ((token & 7) << 4))) = gv;
    }
  __syncthreads();

  // ---- pass C: H = G @ W1^T; pre1 = pre0 + 0.5*H + cvec; tr1 ----
  mmT32(zt, W1b, l15, kof, cb, acc);
  {
    float p[2] = {0.f, 0.f};
    #pragma unroll
    for (int m = 0; m < 4; ++m) {
      f32x4 cvv = *(const f32x4*)&cvec[cb + m * 16 + rg];
      f32x4 dmv = *(const f32x4*)&dM[cb + m * 16 + rg];
      #pragma unroll
      for (int n = 0; n < 2; ++n) {
        float pr0[4] = {bf2f((unsigned short)(p0a[m][n] & 0xffffu)),
                        bf2f((unsigned short)(p0a[m][n] >> 16)),
                        bf2f((unsigned short)(p0b[m][n] & 0xffffu)),
                        bf2f((unsigned short)(p0b[m][n] >> 16))};
        #pragma unroll
        for (int r = 0; r < 4; ++r) {
          float pre = pr0[r] + 0.5f * acc[m][n][r] + cvv[r];
          float e = __expf(-fabsf(pre));
          float rc = __fdividef(1.f, 1.f + e);
          p[n] += ((pre >= 0.f) ? rc : e * rc) * dmv[r];
        }
      }
    }
    #pragma unroll
    for (int n = 0; n < 2; ++n) {
      p[n] += __shfl_xor(p[n], 16);
      p[n] += __shfl_xor(p[n], 32);
    }
    if (lane < 16)
      #pragma unroll
      for (int n = 0; n < 2; ++n) trs[wv][n * 16 + l15] += p[n];
  }
  __syncthreads();

  if (tid < 32) {
    float t = trs[0][tid] + trs[1][tid] + trs[2][tid] + trs[3][tid];
    cbias[tokbase + tid] = -0.5f * znl[tid] - C_LOG2PI + 0.5f * t;
  }
}

// ---------------- big log-prob GEMM ----------------
// Block: 256 h-rows x 64 tokens (4 waves x 64 rows). Swapped MFMA: lane holds
// 4 CONTIGUOUS tokens -> direct f32x4 stores (WRITE_SIZE-verified 202 MB).
// One barrier total. XCD scheme: x = bid&7; stripe = x>>1,
// tc = (x&1)*393 + bid>>3 (contiguous tc per XCD).
__global__ __launch_bounds__(256, 4) void logp_kernel(
    const short* __restrict__ hb, const short* __restrict__ zb,
    const float* __restrict__ hnorm, const float* __restrict__ cbias,
    float* __restrict__ out) {
  __shared__ short Bz[64 * 256];   // 32 KB
  const int bid = blockIdx.x;      // 3144 = 393 * 8
  const int x = bid & 7;
  const int stripe = x >> 1;
  const int tc = (x & 1) * 393 + (bid >> 3);
  const int tokbase = tc * 64;
  const int tid = threadIdx.x;
  const int lane = tid & 63, wv = tid >> 6;
  const int l15 = lane & 15, rg = (lane >> 4) * 4, kof = (lane >> 4) * 8;

  // stage B tile (64 tokens, pre-swizzled rows): linear, conflict-free
  {
    const char* bsrc = (const char*)(zb + (size_t)tokbase * 256);
    #pragma unroll
    for (int it = 0; it < 8; ++it) {
      int uoff = wv * 8192 + it * 1024;
      gload16(bsrc + uoff + lane * 16, (char*)Bz + uoff);
    }
  }
  __syncthreads();

  const int rowbase = stripe * 256 + wv * 64;
  f32x4 acc2[4][4];
  const f32x4 vz = {0.f, 0.f, 0.f, 0.f};
  #pragma unroll
  for (int n = 0; n < 4; ++n)
    #pragma unroll
    for (int m = 0; m < 4; ++m) acc2[n][m] = vz;

  #pragma unroll
  for (int s = 0; s < 8; ++s) {
    int k0 = s * 32 + kof;
    int ks = k0 ^ ((l15 & 7) << 3);
    bf16x8 z[4];
    #pragma unroll
    for (int n = 0; n < 4; ++n)
      z[n] = *(const bf16x8*)&Bz[(n * 16 + l15) * 256 + ks];
    #pragma unroll
    for (int m = 0; m < 4; ++m) {
      bf16x8 a = *(const bf16x8*)&hb[(rowbase + m * 16 + l15) * 256 + k0];
      #pragma unroll
      for (int n = 0; n < 4; ++n) acc2[n][m] = MFMA16(z[n], a, acc2[n][m]);
    }
  }

  // direct stores: gr = h-row (l15), gt = 4 contiguous tokens (rg)
  #pragma unroll
  for (int m = 0; m < 4; ++m) {
    int gr = rowbase + m * 16 + l15;
    float hn = 0.5f * hnorm[gr];
    #pragma unroll
    for (int n = 0; n < 4; ++n) {
      int gt = tokbase + n * 16 + rg;
      f32x4 cb4 = *(const f32x4*)&cbias[gt];
      f32x4 v = acc2[n][m];
      #pragma unroll
      for (int r = 0; r < 4; ++r) v[r] += cb4[r] - hn;
      float* op = out + (size_t)gr * NTOKEN + gt;
      if (gt + 4 <= NTOKEN) {
        *(f32x4u*)op = v;
      } else {
        #pragma unroll
        for (int r = 0; r < 4; ++r)
          if (gt + r < NTOKEN) op[r] = v[r];
      }
    }
  }
}

// ---------------- launcher ----------------
extern "C" void kernel_launch(void* const* d_in, const int* in_sizes, int n_in,
                              void* d_out, int out_size, void* d_ws, size_t ws_size,
                              hipStream_t stream) {
  const float* h   = (const float*)d_in[0];
  const float* emb = (const float*)d_in[1];
  const float* W1x = (const float*)d_in[2];
  const float* w1t = (const float*)d_in[3];
  const float* b1  = (const float*)d_in[4];
  const float* W2  = (const float*)d_in[5];
  const float* b2  = (const float*)d_in[6];
  float* out = (float*)d_out;

  char* ws = (char*)d_ws;
  short* hb    = (short*)(ws + HB_OFF);
  short* zb    = (short*)(ws + ZB_OFF);
  float* hnorm = (float*)(ws + HN_OFF);
  float* cbias = (float*)(ws + CB_OFF);
  float* dM    = (float*)(ws + DM_OFF);
  float* cvec  = (float*)(ws + CV_OFF);
  short* W1b   = (short*)(ws + W1B_OFF);
  short* W2b   = (short*)(ws + W2B_OFF);

  prep_all<<<160, 256, 0, stream>>>(h, W1x, W2, w1t, b2, hb, hnorm, W1b, W2b,
                                    dM, cvec);
  cnf4<<<NTOK_PAD / 32, 256, 0, stream>>>(emb, W1b, W2b, dM, cvec, b1, zb,
                                          cbias);
  logp_kernel<<<393 * 8, 256, 0, stream>>>(hb, zb, hnorm, cbias, out);
}

// Round 11
// 147.652 us; speedup vs baseline: 1.4311x; 1.3444x over previous
//
#include <hip/hip_runtime.h>

#define NTOKEN 50257
#define NTOK_PAD 50304   // 1572 * 32
#define SB 1024
#define C_LOG2PI 235.2482644909f  // 0.5 * 256 * log(2*pi)

typedef __attribute__((ext_vector_type(8))) short bf16x8;
typedef __attribute__((ext_vector_type(4))) short s16x4;
typedef __attribute__((ext_vector_type(4))) float f32x4;
typedef float f32x4u __attribute__((ext_vector_type(4), aligned(4)));

#define MFMA16(a, b, c) __builtin_amdgcn_mfma_f32_16x16x32_bf16((a), (b), (c), 0, 0, 0)

__device__ __forceinline__ unsigned short f2bf(float f) {
  unsigned int u = __float_as_uint(f);
  u += 0x7fffu + ((u >> 16) & 1u);   // round-to-nearest-even
  return (unsigned short)(u >> 16);
}
__device__ __forceinline__ float bf2f(unsigned short s) {
  return __uint_as_float(((unsigned int)s) << 16);
}
__device__ __forceinline__ void gload16(const void* g, void* l) {
  __builtin_amdgcn_global_load_lds(
      (const __attribute__((address_space(1))) unsigned int*)g,
      (__attribute__((address_space(3))) unsigned int*)l, 16, 0, 0);
}

// ---------------- workspace layout (bytes) ----------------
// Fragment-major layout MF[rowblk][s][lane] (16B frags):
//   frag holds M[rowblk*16 + (lane&15)][s*32 + (lane>>4)*8 .. +8] as bf16x8
//   byte offset = rowblk*8192 + s*1024 + lane*16  -> wave load is 1KB stream.
#define HBF_OFF  0u            // 64 rowblk * 8192 = 524288
#define ZB_OFF   524288u       // 50304*256*2 = 25755648 (pre-swizzled rows)
#define HN_OFF   26279936u     // 1024*4
#define CB_OFF   26284032u     // 50304*4
#define DM_OFF   26485248u     // 256*4
#define CV_OFF   26486272u     // 256*4
#define W1F_OFF  26487296u     // 16 rowblk * 8192 = 131072
#define W2F_OFF  26618368u     // 131072 (end = 26749440)

// ---------------- prep: fragment-major hbF/W1F/W2F + hnorm + dM/cvec ----------
// grid = 128 (hbF) + 32 (hnorm) + 32 (WF) + 64 (diag/cvec) = 256 blocks x 256
__global__ __launch_bounds__(256) void prep_all(
    const float* __restrict__ h, const float* __restrict__ W1x,
    const float* __restrict__ W2, const float* __restrict__ w1t,
    const float* __restrict__ b2, char* __restrict__ hbF,
    float* __restrict__ hnorm, char* __restrict__ W1F,
    char* __restrict__ W2F, float* __restrict__ dM,
    float* __restrict__ cvec) {
  const int bid = blockIdx.x;
  const int tid = threadIdx.x;
  if (bid < 128) {
    // ---- h -> fragment-major hbF ----
    int gid = bid * 256 + tid;           // 0..32767
    int rowblk = gid >> 9, rem = gid & 511;
    int s = rem >> 6, ln = rem & 63;
    int srow = rowblk * 16 + (ln & 15);
    int scol = s * 32 + (ln >> 4) * 8;
    const float4* p = (const float4*)&h[srow * 256 + scol];
    float4 x = p[0], y = p[1];
    float v[8] = {x.x, x.y, x.z, x.w, y.x, y.y, y.z, y.w};
    bf16x8 o;
    #pragma unroll
    for (int j = 0; j < 8; ++j) o[j] = (short)f2bf(v[j]);
    *(bf16x8*)(hbF + (size_t)gid * 16) = o;
  } else if (bid < 160) {
    // ---- h row norms ----
    int row = (bid - 128) * 32 + (tid >> 3);
    int c0 = (tid & 7) * 32;
    float ss = 0.f;
    #pragma unroll
    for (int g = 0; g < 4; ++g) {
      const float4* p = (const float4*)&h[row * 256 + c0 + g * 8];
      float4 x = p[0], y = p[1];
      ss += x.x * x.x + x.y * x.y + x.z * x.z + x.w * x.w;
      ss += y.x * y.x + y.y * y.y + y.z * y.z + y.w * y.w;
    }
    ss += __shfl_xor(ss, 1); ss += __shfl_xor(ss, 2); ss += __shfl_xor(ss, 4);
    if ((tid & 7) == 0) hnorm[row] = ss;
  } else if (bid < 192) {
    // ---- W1x, W2 -> fragment-major W1F/W2F ----
    int gid = (bid - 160) * 256 + tid;   // 0..8191
    int rowblk = gid >> 9, rem = gid & 511;
    int s = rem >> 6, ln = rem & 63;
    int srow = rowblk * 16 + (ln & 15);
    int scol = s * 32 + (ln >> 4) * 8;
    {
      const float4* p = (const float4*)&W1x[srow * 256 + scol];
      float4 x = p[0], y = p[1];
      float v[8] = {x.x, x.y, x.z, x.w, y.x, y.y, y.z, y.w};
      bf16x8 o;
      #pragma unroll
      for (int j = 0; j < 8; ++j) o[j] = (short)f2bf(v[j]);
      *(bf16x8*)(W1F + (size_t)gid * 16) = o;
    }
    {
      const float4* p = (const float4*)&W2[srow * 256 + scol];
      float4 x = p[0], y = p[1];
      float v[8] = {x.x, x.y, x.z, x.w, y.x, y.y, y.z, y.w};
      bf16x8 o;
      #pragma unroll
      for (int j = 0; j < 8; ++j) o[j] = (short)f2bf(v[j]);
      *(bf16x8*)(W2F + (size_t)gid * 16) = o;
    }
  } else {
    // ---- dM[j] = sum_i W1x[j,i]*W2[i,j]; cvec[j] = .5*(W1x[j,:]·b2 + w1t[j]) ----
    int j = (bid - 192) * 4 + (tid >> 6);
    int lane = tid & 63;
    float s = 0.f, s2 = 0.f;
    #pragma unroll
    for (int t = 0; t < 4; ++t) {
      int i = lane + t * 64;
      float w1 = W1x[j * 256 + i];
      s += w1 * W2[i * 256 + j];
      s2 += w1 * b2[i];
    }
    #pragma unroll
    for (int d = 1; d < 64; d <<= 1) {
      s += __shfl_xor(s, d);
      s2 += __shfl_xor(s2, d);
    }
    if (lane == 0) { dM[j] = s; cvec[j] = 0.5f * (s2 + w1t[j]); }
  }
}

// ---- 32x256 LDS tile (token rows, XOR-swizzled 16B groups) x fragment-major W
// acc[m][n] = MFMA16(Wfrag[m], Tfrag[n]) -> D[wcol][token]:
//   wcol = cb + m*16 + rg + r (contiguous in r), token = n*16 + l15.
__device__ __forceinline__ void mmT32(const short* T, const char* __restrict__ WF,
                                      int l15, int lane, int wv, f32x4 acc[4][2]) {
  const f32x4 vz = {0.f, 0.f, 0.f, 0.f};
  #pragma unroll
  for (int m = 0; m < 4; ++m)
    #pragma unroll
    for (int n = 0; n < 2; ++n) acc[m][n] = vz;
  const int kof = (lane >> 4) * 8;
  const char* wbase = WF + (size_t)wv * 4 * 8192 + lane * 16;
  #pragma unroll
  for (int s = 0; s < 8; ++s) {
    int ks = (s * 32 + kof) ^ ((l15 & 7) << 3);
    bf16x8 z[2];
    #pragma unroll
    for (int n = 0; n < 2; ++n)
      z[n] = *(const bf16x8*)&T[(n * 16 + l15) * 256 + ks];
    #pragma unroll
    for (int m = 0; m < 4; ++m) {
      bf16x8 w = *(const bf16x8*)(wbase + m * 8192 + s * 1024);  // 1KB stream
      #pragma unroll
      for (int n = 0; n < 2; ++n) acc[m][n] = MFMA16(w, z[n], acc[m][n]);
    }
  }
}

// ---------------- CNF: 32-token tile, z0 -> sp -> G in place ----------------
// Also produces zb (pre-swizzled bf16 copy of z0) and cbias.
__global__ __launch_bounds__(256, 2) void cnf4(
    const float* __restrict__ emb, const char* __restrict__ W1F,
    const char* __restrict__ W2F, const float* __restrict__ dM,
    const float* __restrict__ cvec, const float* __restrict__ b1,
    short* __restrict__ zb, float* __restrict__ cbias) {
  __shared__ short zt[32 * 256];    // 16 KB: z0 -> sp -> G
  __shared__ float trs[4][32];
  __shared__ float znl[32];
  const int tid = threadIdx.x;
  const int lane = tid & 63, wv = tid >> 6;
  const int l15 = lane & 15, rg = (lane >> 4) * 4;
  const int cb = wv * 64;
  const int tokbase = blockIdx.x * 32;

  // ---- stage z0: slot-linear LDS writes (conflict-free), XOR folded into
  // the global read; also emit zb (coalesced) + row norms via 32-lane shfl ----
  #pragma unroll
  for (int k = 0; k < 4; ++k) {
    int o = tid + k * 256;
    int row = o >> 5, blk = o & 31;
    int g = (blk & 24) | ((blk & 7) ^ (row & 7));
    int gtok = tokbase + row;
    float v[8];
    if (gtok < NTOKEN) {
      const float4* p = (const float4*)&emb[(size_t)gtok * 256 + g * 8];
      float4 x = p[0], y = p[1];
      v[0] = x.x; v[1] = x.y; v[2] = x.z; v[3] = x.w;
      v[4] = y.x; v[5] = y.y; v[6] = y.z; v[7] = y.w;
    } else {
      #pragma unroll
      for (int j = 0; j < 8; ++j) v[j] = 0.f;
    }
    bf16x8 ob;
    float ss = 0.f;
    #pragma unroll
    for (int j = 0; j < 8; ++j) { ss += v[j] * v[j]; ob[j] = (short)f2bf(v[j]); }
    *(bf16x8*)((char*)zt + o * 16) = ob;
    *(bf16x8*)&zb[(size_t)tokbase * 256 + o * 8] = ob;
    ss += __shfl_xor(ss, 1); ss += __shfl_xor(ss, 2); ss += __shfl_xor(ss, 4);
    ss += __shfl_xor(ss, 8); ss += __shfl_xor(ss, 16);
    if ((tid & 31) == 0) znl[(tid >> 5) + k * 8] = ss;
  }
  __syncthreads();

  f32x4 acc[4][2];
  unsigned int p0a[4][2], p0b[4][2];   // pre0 packed 2xbf16 (16 VGPR)

  // ---- pass A: pre0^T = W1 x z0; tr0; sp -> zt ----
  mmT32(zt, W1F, l15, lane, wv, acc);
  __syncthreads();   // all waves done reading z0
  {
    float p[2] = {0.f, 0.f};
    #pragma unroll
    for (int m = 0; m < 4; ++m) {
      f32x4 b1v = *(const f32x4*)&b1[cb + m * 16 + rg];
      f32x4 dmv = *(const f32x4*)&dM[cb + m * 16 + rg];
      #pragma unroll
      for (int n = 0; n < 2; ++n) {
        s16x4 spv;
        float pre[4];
        #pragma unroll
        for (int r = 0; r < 4; ++r) {
          pre[r] = acc[m][n][r] + b1v[r];
          float e = __expf(-fabsf(pre[r]));
          float rc = __fdividef(1.f, 1.f + e);
          p[n] += ((pre[r] >= 0.f) ? rc : e * rc) * dmv[r];
          spv[r] = (short)f2bf(fmaxf(pre[r], 0.f) + __logf(1.f + e));
        }
        p0a[m][n] = (unsigned int)f2bf(pre[0]) | ((unsigned int)f2bf(pre[1]) << 16);
        p0b[m][n] = (unsigned int)f2bf(pre[2]) | ((unsigned int)f2bf(pre[3]) << 16);
        int token = n * 16 + l15;
        int colb = (cb + m * 16 + rg) * 2;
        *(s16x4*)((char*)zt + token * 512 + (colb ^ ((token & 7) << 4))) = spv;
      }
    }
    #pragma unroll
    for (int n = 0; n < 2; ++n) {
      p[n] += __shfl_xor(p[n], 16);
      p[n] += __shfl_xor(p[n], 32);
    }
    if (lane < 16)
      #pragma unroll
      for (int n = 0; n < 2; ++n) trs[wv][n * 16 + l15] = p[n];
  }
  __syncthreads();

  // ---- pass B: G = sp @ W2^T -> zt ----
  mmT32(zt, W2F, l15, lane, wv, acc);
  __syncthreads();   // all waves done reading sp
  #pragma unroll
  for (int m = 0; m < 4; ++m)
    #pragma unroll
    for (int n = 0; n < 2; ++n) {
      s16x4 gv;
      #pragma unroll
      for (int r = 0; r < 4; ++r) gv[r] = (short)f2bf(acc[m][n][r]);
      int token = n * 16 + l15;
      int colb = (cb + m * 16 + rg) * 2;
      *(s16x4*)((char*)zt + token * 512 + (colb ^ ((token & 7) << 4))) = gv;
    }
  __syncthreads();

  // ---- pass C: H = G @ W1^T; pre1 = pre0 + 0.5*H + cvec; tr1 ----
  mmT32(zt, W1F, l15, lane, wv, acc);
  {
    float p[2] = {0.f, 0.f};
    #pragma unroll
    for (int m = 0; m < 4; ++m) {
      f32x4 cvv = *(const f32x4*)&cvec[cb + m * 16 + rg];
      f32x4 dmv = *(const f32x4*)&dM[cb + m * 16 + rg];
      #pragma unroll
      for (int n = 0; n < 2; ++n) {
        float pr0[4] = {bf2f((unsigned short)(p0a[m][n] & 0xffffu)),
                        bf2f((unsigned short)(p0a[m][n] >> 16)),
                        bf2f((unsigned short)(p0b[m][n] & 0xffffu)),
                        bf2f((unsigned short)(p0b[m][n] >> 16))};
        #pragma unroll
        for (int r = 0; r < 4; ++r) {
          float pre = pr0[r] + 0.5f * acc[m][n][r] + cvv[r];
          float e = __expf(-fabsf(pre));
          float rc = __fdividef(1.f, 1.f + e);
          p[n] += ((pre >= 0.f) ? rc : e * rc) * dmv[r];
        }
      }
    }
    #pragma unroll
    for (int n = 0; n < 2; ++n) {
      p[n] += __shfl_xor(p[n], 16);
      p[n] += __shfl_xor(p[n], 32);
    }
    if (lane < 16)
      #pragma unroll
      for (int n = 0; n < 2; ++n) trs[wv][n * 16 + l15] += p[n];
  }
  __syncthreads();

  if (tid < 32) {
    float t = trs[0][tid] + trs[1][tid] + trs[2][tid] + trs[3][tid];
    cbias[tokbase + tid] = -0.5f * znl[tid] - C_LOG2PI + 0.5f * t;
  }
}

// ---------------- big log-prob GEMM ----------------
// Block: 256 h-rows x 64 tokens (4 waves x 64 rows). A = fragment-major hbF
// (1KB streamed wave-loads); B = zb staged via gload16. Swapped MFMA: lane
// holds 4 CONTIGUOUS tokens -> direct f32x4 stores (WRITE-verified 202 MB).
// XCD scheme: x = bid&7; stripe = x>>1, tc = (x&1)*393 + bid>>3.
__global__ __launch_bounds__(256, 4) void logp_kernel(
    const char* __restrict__ hbF, const short* __restrict__ zb,
    const float* __restrict__ hnorm, const float* __restrict__ cbias,
    float* __restrict__ out) {
  __shared__ short Bz[64 * 256];   // 32 KB
  const int bid = blockIdx.x;      // 3144 = 393 * 8
  const int x = bid & 7;
  const int stripe = x >> 1;
  const int tc = (x & 1) * 393 + (bid >> 3);
  const int tokbase = tc * 64;
  const int tid = threadIdx.x;
  const int lane = tid & 63, wv = tid >> 6;
  const int l15 = lane & 15, rg = (lane >> 4) * 4, kof = (lane >> 4) * 8;

  // stage B tile (64 tokens, pre-swizzled rows): linear, conflict-free
  {
    const char* bsrc = (const char*)(zb + (size_t)tokbase * 256);
    #pragma unroll
    for (int it = 0; it < 8; ++it) {
      int uoff = wv * 8192 + it * 1024;
      gload16(bsrc + uoff + lane * 16, (char*)Bz + uoff);
    }
  }
  __syncthreads();

  f32x4 acc2[4][4];
  const f32x4 vz = {0.f, 0.f, 0.f, 0.f};
  #pragma unroll
  for (int n = 0; n < 4; ++n)
    #pragma unroll
    for (int m = 0; m < 4; ++m) acc2[n][m] = vz;

  const char* abase = hbF + (size_t)(stripe * 16 + wv * 4) * 8192 + lane * 16;
  #pragma unroll
  for (int s = 0; s < 8; ++s) {
    int ks = (s * 32 + kof) ^ ((l15 & 7) << 3);
    bf16x8 z[4];
    #pragma unroll
    for (int n = 0; n < 4; ++n)
      z[n] = *(const bf16x8*)&Bz[(n * 16 + l15) * 256 + ks];
    #pragma unroll
    for (int m = 0; m < 4; ++m) {
      bf16x8 a = *(const bf16x8*)(abase + m * 8192 + s * 1024);  // 1KB stream
      #pragma unroll
      for (int n = 0; n < 4; ++n) acc2[n][m] = MFMA16(z[n], a, acc2[n][m]);
    }
  }

  // direct stores: gr = h-row (l15), gt = 4 contiguous tokens (rg)
  const int rowbase = stripe * 256 + wv * 64;
  #pragma unroll
  for (int m = 0; m < 4; ++m) {
    int gr = rowbase + m * 16 + l15;
    float hn = 0.5f * hnorm[gr];
    #pragma unroll
    for (int n = 0; n < 4; ++n) {
      int gt = tokbase + n * 16 + rg;
      f32x4 cb4 = *(const f32x4*)&cbias[gt];
      f32x4 v = acc2[n][m];
      #pragma unroll
      for (int r = 0; r < 4; ++r) v[r] += cb4[r] - hn;
      float* op = out + (size_t)gr * NTOKEN + gt;
      if (gt + 4 <= NTOKEN) {
        *(f32x4u*)op = v;
      } else {
        #pragma unroll
        for (int r = 0; r < 4; ++r)
          if (gt + r < NTOKEN) op[r] = v[r];
      }
    }
  }
}

// ---------------- launcher ----------------
extern "C" void kernel_launch(void* const* d_in, const int* in_sizes, int n_in,
                              void* d_out, int out_size, void* d_ws, size_t ws_size,
                              hipStream_t stream) {
  const float* h   = (const float*)d_in[0];
  const float* emb = (const float*)d_in[1];
  const float* W1x = (const float*)d_in[2];
  const float* w1t = (const float*)d_in[3];
  const float* b1  = (const float*)d_in[4];
  const float* W2  = (const float*)d_in[5];
  const float* b2  = (const float*)d_in[6];
  float* out = (float*)d_out;

  char* ws = (char*)d_ws;
  char*  hbF   = ws + HBF_OFF;
  short* zb    = (short*)(ws + ZB_OFF);
  float* hnorm = (float*)(ws + HN_OFF);
  float* cbias = (float*)(ws + CB_OFF);
  float* dM    = (float*)(ws + DM_OFF);
  float* cvec  = (float*)(ws + CV_OFF);
  char*  W1F   = ws + W1F_OFF;
  char*  W2F   = ws + W2F_OFF;

  prep_all<<<256, 256, 0, stream>>>(h, W1x, W2, w1t, b2, hbF, hnorm, W1F, W2F,
                                    dM, cvec);
  cnf4<<<NTOK_PAD / 32, 256, 0, stream>>>(emb, W1F, W2F, dM, cvec, b1, zb,
                                          cbias);
  logp_kernel<<<393 * 8, 256, 0, stream>>>(hbF, zb, hnorm, cbias, out);
}